// Round 12
// baseline (255.180 us; speedup 1.0000x reference)
//
#include <hip/hip_runtime.h>
#include <stdint.h>

#define B_ 2
#define T_ 4096
#define D_ 768
#define H_ 12
#define DK_ 64
#define BH_ 24

typedef unsigned short u16;
typedef unsigned int u32;
typedef __bf16 bf16x8 __attribute__((ext_vector_type(8)));
typedef float f32x4 __attribute__((ext_vector_type(4)));
typedef short s16x8 __attribute__((ext_vector_type(8)));

__device__ __forceinline__ float exp2_raw(float x) {
#if __has_builtin(__builtin_amdgcn_exp2f)
    return __builtin_amdgcn_exp2f(x);
#else
    float y; asm("v_exp_f32 %0, %1" : "=v"(y) : "v"(x)); return y;
#endif
}

__device__ __forceinline__ f32x4 mfma16(bf16x8 a, bf16x8 b, f32x4 c) {
    return __builtin_amdgcn_mfma_f32_16x16x32_bf16(a, b, c, 0, 0, 0);
}

__device__ __forceinline__ u16 f2bf(float f) {
    union { float f; u32 u; } v; v.f = f;
    u32 r = v.u + 0x7FFFu + ((v.u >> 16) & 1u);
    return (u16)(r >> 16);
}

// pack two floats to bf16 pair (lo | hi<<16), round-half-up, via v_perm
__device__ __forceinline__ u32 pack2bf(float lo, float hi) {
    union { float f; u32 u; } a, b; a.f = lo; b.f = hi;
    return __builtin_amdgcn_perm(b.u + 0x8000u, a.u + 0x8000u, 0x07060302u);
}

// async 16B global->LDS; lds base must be wave-uniform, lane i lands at base+i*16
__device__ __forceinline__ void gll16(const u16* g, u16* l) {
    __builtin_amdgcn_global_load_lds(
        (const __attribute__((address_space(1))) u32*)g,
        (__attribute__((address_space(3))) u32*)l, 16, 0, 0);
}

// ------- prep: x fp32->bf16 (bid<3072) + weight transpose (bid>=3072) -------
// merged to save one kernel-launch gap (~10us).
__global__ __launch_bounds__(256) void prep_kernel(
    const float* __restrict__ x,
    const float* __restrict__ w0, const float* __restrict__ w1,
    const float* __restrict__ w2, const float* __restrict__ w3,
    u16* __restrict__ xb, u16* __restrict__ wt)
{
    __shared__ u16 tile[32][33];
    int bid = blockIdx.x;
    if (bid < 3072) {
        int i = (bid * 256 + threadIdx.x) * 8;
        float4 a = *(const float4*)&x[i];
        float4 b = *(const float4*)&x[i + 4];
        uint4 dd;
        dd.x = pack2bf(a.x, a.y); dd.y = pack2bf(a.z, a.w);
        dd.z = pack2bf(b.x, b.y); dd.w = pack2bf(b.z, b.w);
        *(uint4*)&xb[i] = dd;
    } else {
        int id = bid - 3072;            // 2304 = 4 * 24 * 24
        int z = id / 576;
        int rest = id % 576;
        int by = rest / 24, bx = rest % 24;
        const float* src = (z == 0) ? w0 : (z == 1) ? w1 : (z == 2) ? w2 : w3;
        u16* dst = wt + (size_t)z * D_ * D_;
        int tx = threadIdx.x & 31, ty = threadIdx.x >> 5;
        int x0 = bx * 32, y0 = by * 32;
        for (int i = ty; i < 32; i += 8) tile[i][tx] = f2bf(src[(size_t)(y0 + i) * D_ + x0 + tx]);
        __syncthreads();
        for (int i = ty; i < 32; i += 8) dst[(size_t)(x0 + i) * D_ + y0 + tx] = tile[tx][i];
    }
}

// ---------------- GEMM: C[M][N] = A[M][K] * Bt[N][K]^T, K=768 ---------------
// m97-style: global_load_lds 16B staging, unpadded LDS with XOR chunk swizzle
// LDS[row][c8] holds global chunk c8 ^ (row&7); swizzle realized on global side.
// T1 XCD swizzle (flat grid): xcd = wgid%8 owns a CONTIGUOUS m-range (8 m-tiles
// x all n-tiles) -> per-XCD L2 working set = A-slice 1.6MB + full B (3.4/1.2MB)
// ~resident, vs default n-fastest round-robin thrashing all 8 L2s with 16MB.
// MODE 0: A bf16 x, N=2304 fused QKV (Q scaled, K, V transposed). MODE 1: fp32 out.
template<int MODE>
__global__ __launch_bounds__(256) void gemm_bt(
    const u16* __restrict__ A, const u16* __restrict__ Bt, void* __restrict__ outv)
{
    __shared__ u16 As[128 * 64];
    __shared__ u16 Bs[128 * 64];
    const int K = 768;
    const int NT = (MODE == 0) ? 18 : 6;   // n-tiles
    int tid = threadIdx.x;
    int lane = tid & 63, wave = tid >> 6;
    int r = lane & 15, quad = lane >> 4;
    int rx = r & 7;

    // XCD-aware decode: 64 m-tiles = 8 per XCD, contiguous.
    int wgid = blockIdx.x;
    int xcd = wgid & 7, slot = wgid >> 3;      // slot in [0, 8*NT)
    int mt = xcd * 8 + slot / NT;
    int nt = slot % NT;
    int m0 = mt * 128, n0 = nt * 128;
    int wrow = (wave >> 1) * 64, wcol = (wave & 1) * 64;

    // staging: lane l covers row = wave*32 + j*8 + (l>>3), global chunk (l&7)^((l>>3)&7)
    int srow = wave * 32 + (lane >> 3);
    int scol = ((lane & 7) ^ (lane >> 3)) * 8;
    const u16* Ag = A + (size_t)(m0 + srow) * K + scol;
    const u16* Bg = Bt + (size_t)(n0 + srow) * K + scol;

    f32x4 acc[4][4];
    #pragma unroll
    for (int i = 0; i < 4; i++)
        #pragma unroll
        for (int j = 0; j < 4; j++)
            #pragma unroll
            for (int e = 0; e < 4; e++) acc[i][j][e] = 0.f;

    for (int k0 = 0; k0 < K; k0 += 64) {
        __syncthreads();
        #pragma unroll
        for (int j = 0; j < 4; j++) {
            gll16(Ag + (size_t)j * 8 * K + k0, As + (wave * 32 + j * 8) * 64);
            gll16(Bg + (size_t)j * 8 * K + k0, Bs + (wave * 32 + j * 8) * 64);
        }
        __syncthreads();
        #pragma unroll
        for (int ks = 0; ks < 2; ks++) {
            int swz = ((ks * 4 + quad) ^ rx) * 8;
            bf16x8 af[4], bfr[4];
            #pragma unroll
            for (int mi = 0; mi < 4; mi++)
                af[mi] = *(const bf16x8*)&As[(wrow + mi * 16 + r) * 64 + swz];
            #pragma unroll
            for (int ni = 0; ni < 4; ni++)
                bfr[ni] = *(const bf16x8*)&Bs[(wcol + ni * 16 + r) * 64 + swz];
            #pragma unroll
            for (int mi = 0; mi < 4; mi++)
                #pragma unroll
                for (int ni = 0; ni < 4; ni++)
                    acc[mi][ni] = mfma16(af[mi], bfr[ni], acc[mi][ni]);
        }
    }

    if (MODE == 0) {
        u16* out = (u16*)outv;
        int which = n0 / D_;
        int nb = n0 % D_;
        const size_t HS = (size_t)B_ * H_ * T_ * DK_;
        if (which == 2) {
            u16* vt = out + 2 * HS;
            #pragma unroll
            for (int mi = 0; mi < 4; mi++) {
                int mg = m0 + wrow + mi * 16 + quad * 4;
                int b = mg >> 12, t = mg & 4095;
                #pragma unroll
                for (int ni = 0; ni < 4; ni++) {
                    int ng = nb + wcol + ni * 16 + r;
                    int h = ng >> 6, dk = ng & 63;
                    uint2 d;
                    d.x = pack2bf(acc[mi][ni][0], acc[mi][ni][1]);
                    d.y = pack2bf(acc[mi][ni][2], acc[mi][ni][3]);
                    *(uint2*)&vt[(((size_t)(b * H_ + h)) * DK_ + dk) * T_ + t] = d;
                }
            }
        } else {
            const float cf = (which == 0) ? 0.18033688011112042f : 1.0f; // 0.125*log2(e)
            size_t wbase = (size_t)which * HS;
            #pragma unroll
            for (int mi = 0; mi < 4; mi++) {
                #pragma unroll
                for (int ni = 0; ni < 4; ni++) {
                    int ng = nb + wcol + ni * 16 + r;
                    int h = ng >> 6, dk = ng & 63;
                    #pragma unroll
                    for (int e = 0; e < 4; e++) {
                        int mg = m0 + wrow + mi * 16 + quad * 4 + e;
                        int b = mg >> 12, t = mg & 4095;
                        out[wbase + (((size_t)(b * H_ + h)) * T_ + t) * DK_ + dk]
                            = f2bf(acc[mi][ni][e] * cf);
                    }
                }
            }
        }
    } else {
        float* out = (float*)outv;
        #pragma unroll
        for (int mi = 0; mi < 4; mi++)
            #pragma unroll
            for (int ni = 0; ni < 4; ni++)
                #pragma unroll
                for (int e = 0; e < 4; e++)
                    out[(size_t)(m0 + wrow + mi * 16 + quad * 4 + e) * D_ + n0 + wcol + ni * 16 + r]
                        = acc[mi][ni][e];
    }
}

// ---------------- flash attention: S^T, no-max, KV-split, q=32/wave ---------
// Q (pre-scaled), K: [bh][t][dk]; VT: [bh][dk][t]
// Block: 512 threads = 8 waves x 32 q rows (256 q per block), kv tile 128.
// P stays IN REGISTERS: QK^T MFMA (s,p) feeds K rows perm(i)=s*32+(i>>2)*8+p*4+(i&3),
// so each lane's C-rows (quad*4+e) land exactly on its PV B-fragment kv slots
// (kv = s*32+quad*8+j), s in 0..3. No Pt LDS buffer, no cross-lane exchange.
// V held as TWO [64][64] subtiles per buffer (R9: conflict-free).
// T3 minimum-2-phase with COMPILE-TIME ping-pong: STAGE(next buf) issued before
// COMPUTE(cur buf); the vmcnt(0) inside the single per-tile __syncthreads then
// drains loads issued a full compute phase earlier (hidden).
// Staging via global_load_lds: linear LDS dest + pre-XOR'd global chunk (rule #21).
// T1 XCD swizzle: flat 768-block grid; xcd = wgid%8 owns 3 bh -> K+V (3MB) in L2.
__global__ __launch_bounds__(512, 4) void attn_kernel(
    const u16* __restrict__ Q, const u16* __restrict__ K,
    const u16* __restrict__ VT, float* __restrict__ pO, float* __restrict__ pL)
{
    __shared__ u16 Ks[2][128 * 64];      // [buf][kv][dk], chunk-swizzled
    __shared__ u16 Vs[2][2][64 * 64];    // [buf][kvhalf][dk][kv64], chunk-swizzled

    int tid = threadIdx.x;
    int lane = tid & 63, w = tid >> 6;       // w in [0,8)
    int r = lane & 15, quad = lane >> 4;

    // XCD-aware decode of flat wgid (768 = 8 xcd * 3 bh * 2 z * 16 qblk)
    int wgid = blockIdx.x;
    int xcd = wgid & 7, slot = wgid >> 3;
    int bh = xcd * 3 + (slot >> 5);
    int rem = slot & 31;
    int z = rem >> 4;
    int q0 = (rem & 15) * 256;

    bf16x8 qf[2][2];
    #pragma unroll
    for (int qi = 0; qi < 2; qi++) {
        const u16* Qb = Q + ((size_t)bh * T_ + q0 + w * 32 + qi * 16 + r) * DK_;
        qf[qi][0] = *(const bf16x8*)(Qb + quad * 8);
        qf[qi][1] = *(const bf16x8*)(Qb + 32 + quad * 8);
    }

    bf16x8 ones;
    #pragma unroll
    for (int j = 0; j < 8; j++) ones[j] = (__bf16)1.0f;

    f32x4 fzero;
    #pragma unroll
    for (int e = 0; e < 4; e++) fzero[e] = 0.f;

    f32x4 o[2][4];      // [qi][ndk]
    f32x4 lacc[2];
    #pragma unroll
    for (int qi = 0; qi < 2; qi++) {
        #pragma unroll
        for (int e = 0; e < 4; e++) lacc[qi][e] = 0.f;
        #pragma unroll
        for (int n = 0; n < 4; n++)
            #pragma unroll
            for (int e = 0; e < 4; e++) o[qi][n][e] = 0.f;
    }

    int kb0 = z * (T_ / 2), kb1 = kb0 + T_ / 2;
    int rb = ((r >> 2) * 8) + (r & 3);   // base of permuted K row for this lane

    // K staging: wave w stages rows w*16+(lane>>3) and w*16+8+(lane>>3).
    // f(row): group1 row>>3 = 2w (even) -> f=(lane>>3)&3; group2 -> f^4.
    int kls = lane >> 3;
    int sgcK1 = (lane & 7) ^ (kls & 3);
    const u16* KgA = K + ((size_t)bh * T_ + w * 16 + kls) * DK_ + sgcK1 * 8;
    const u16* KgB = K + ((size_t)bh * T_ + w * 16 + 8 + kls) * DK_ + (sgcK1 ^ 4) * 8;

    // V staging (R7 pattern per subtile): wave w covers dk rows w*8+(lane>>3),
    // local chunk (lane&7)^f(row); subtile j covers kv kb+j*64.
    int srow = w * 8 + (lane >> 3);
    int sfr = (w & 1) * 4 + ((lane >> 3) & 3);      // f(srow)
    int sgcV = (lane & 7) ^ sfr;
    const u16* Vg = VT + ((size_t)bh * DK_ + srow) * T_ + sgcV * 8;

    // per-buffer LDS staging bases (compile-time buffer selection)
    u16* KsA0 = &Ks[0][(w * 16) * 64];
    u16* KsB0 = &Ks[0][(w * 16 + 8) * 64];
    u16* KsA1 = &Ks[1][(w * 16) * 64];
    u16* KsB1 = &Ks[1][(w * 16 + 8) * 64];
    u16* V00 = &Vs[0][0][(w * 8) * 64];
    u16* V01 = &Vs[0][1][(w * 8) * 64];
    u16* V10 = &Vs[1][0][(w * 8) * 64];
    u16* V11 = &Vs[1][1][(w * 8) * 64];

    auto stage_tile = [&](int kb, u16* ksA, u16* ksB, u16* vs0, u16* vs1) {
        gll16(KgA + (size_t)kb * DK_, ksA);
        gll16(KgB + (size_t)kb * DK_, ksB);
        gll16(Vg + kb, vs0);
        gll16(Vg + kb + 64, vs1);
    };

    auto compute_tile = [&](const u16* Kc, const u16* V0, const u16* V1) {
        #pragma unroll
        for (int s = 0; s < 4; s++) {
            // K fragments, permuted rows: p=0 -> rowA, p=1 -> rowB
            int rowA = s * 32 + rb;
            int rowB = rowA + 4;
            int fA = ((rowA >> 3) & 1) * 4 + (rowA & 3);
            int fB = ((rowB >> 3) & 1) * 4 + (rowB & 3);
            bf16x8 kA0 = *(const bf16x8*)&Kc[rowA * 64 + (quad ^ fA) * 8];
            bf16x8 kA1 = *(const bf16x8*)&Kc[rowA * 64 + (((4 + quad) ^ fA)) * 8];
            bf16x8 kB0 = *(const bf16x8*)&Kc[rowB * 64 + (quad ^ fB) * 8];
            bf16x8 kB1 = *(const bf16x8*)&Kc[rowB * 64 + (((4 + quad) ^ fB)) * 8];
            // V fragments: subtile s>>1, local chunk ((s&1)*4+quad) ^ f(row)
            const u16* Vsub = (s < 2) ? V0 : V1;
            bf16x8 vf[4];
            #pragma unroll
            for (int ndk = 0; ndk < 4; ndk++) {
                int row = ndk * 16 + r;
                int fvr = ((row >> 3) & 1) * 4 + (row & 3);
                vf[ndk] = *(const bf16x8*)&Vsub[row * 64 + ((((s & 1) * 4 + quad) ^ fvr)) * 8];
            }
            #pragma unroll
            for (int qi = 0; qi < 2; qi++) {
                f32x4 zA, zB;
                zA = mfma16(kA0, qf[qi][0], fzero);
                zA = mfma16(kA1, qf[qi][1], zA);
                zB = mfma16(kB0, qf[qi][0], fzero);
                zB = mfma16(kB1, qf[qi][1], zB);
                // P fragment: lane's 8 slots = kv s*32+quad*8+{0..7}, q col = qi*16+r
                bf16x8 pf;
                pf[0] = (__bf16)exp2_raw(zA[0]);
                pf[1] = (__bf16)exp2_raw(zA[1]);
                pf[2] = (__bf16)exp2_raw(zA[2]);
                pf[3] = (__bf16)exp2_raw(zA[3]);
                pf[4] = (__bf16)exp2_raw(zB[0]);
                pf[5] = (__bf16)exp2_raw(zB[1]);
                pf[6] = (__bf16)exp2_raw(zB[2]);
                pf[7] = (__bf16)exp2_raw(zB[3]);
                lacc[qi] = mfma16(ones, pf, lacc[qi]);
                #pragma unroll
                for (int ndk = 0; ndk < 4; ndk++)
                    o[qi][ndk] = mfma16(vf[ndk], pf, o[qi][ndk]);
            }
        }
    };

    // prologue: stage first tile into buf0
    stage_tile(kb0, KsA0, KsB0, V00, V01);
    __syncthreads();

    for (int kb = kb0; kb < kb1; kb += 256) {
        // issue next tile into buf1; latency hides under compute(buf0)
        stage_tile(kb + 128, KsA1, KsB1, V10, V11);
        compute_tile(Ks[0], Vs[0][0], Vs[0][1]);
        __syncthreads();   // buf1 staged loads drained (hidden); buf0 free
        if (kb + 256 < kb1)
            stage_tile(kb + 256, KsA0, KsB0, V00, V01);
        compute_tile(Ks[1], Vs[1][0], Vs[1][1]);
        __syncthreads();   // buf0 staged loads drained; buf1 free
    }

    // partial epilogue: pO[z][bh][q][dk] fp32, pL[z][bh][q]
    const size_t SP = (size_t)BH_ * T_ * DK_;
    #pragma unroll
    for (int qi = 0; qi < 2; qi++) {
        int q = q0 + w * 32 + qi * 16 + r;
        float* base = pO + (size_t)z * SP + ((size_t)bh * T_ + q) * DK_;
        #pragma unroll
        for (int ndk = 0; ndk < 4; ndk++)
            *(f32x4*)&base[ndk * 16 + quad * 4] = o[qi][ndk];
    }
    if (quad == 0) {
        #pragma unroll
        for (int qi = 0; qi < 2; qi++)
            pL[(size_t)z * BH_ * T_ + (size_t)bh * T_ + q0 + w * 32 + qi * 16 + r]
                = lacc[qi][0];
    }
}

// ---------------- combine: AO = (O0+O1)/(l0+l1), bf16 -----------------------
__global__ __launch_bounds__(256) void combine_kernel(
    const float* __restrict__ pO, const float* __restrict__ pL, u16* __restrict__ AO)
{
    const size_t SP = (size_t)BH_ * T_ * DK_;
    int bh = blockIdx.y;
    int b = bh / H_, h = bh % H_;
    int q = blockIdx.x * 64 + (threadIdx.x >> 2);
    int dk0 = (threadIdx.x & 3) * 16;
    size_t idx = ((size_t)bh * T_ + q) * DK_ + dk0;
    float l0 = pL[(size_t)bh * T_ + q];
    float l1 = pL[(size_t)BH_ * T_ + (size_t)bh * T_ + q];
    float inv = 1.0f / (l0 + l1);
    u16* dst = AO + ((size_t)b * T_ + q) * D_ + h * DK_ + dk0;
    #pragma unroll
    for (int i = 0; i < 2; i++) {
        float4 a0 = *(const float4*)&pO[idx + i * 8];
        float4 a1 = *(const float4*)&pO[idx + i * 8 + 4];
        float4 b0 = *(const float4*)&pO[SP + idx + i * 8];
        float4 b1 = *(const float4*)&pO[SP + idx + i * 8 + 4];
        uint4 dd;
        dd.x = pack2bf((a0.x + b0.x) * inv, (a0.y + b0.y) * inv);
        dd.y = pack2bf((a0.z + b0.z) * inv, (a0.w + b0.w) * inv);
        dd.z = pack2bf((a1.x + b1.x) * inv, (a1.y + b1.y) * inv);
        dd.w = pack2bf((a1.z + b1.z) * inv, (a1.w + b1.w) * inv);
        *(uint4*)&dst[i * 8] = dd;
    }
}

// ---------------- launch -----------------------------------------------------
extern "C" void kernel_launch(void* const* d_in, const int* in_sizes, int n_in,
                              void* d_out, int out_size, void* d_ws, size_t ws_size,
                              hipStream_t stream)
{
    const float* x  = (const float*)d_in[0];
    const float* wq = (const float*)d_in[1];
    const float* wk = (const float*)d_in[2];
    const float* wv = (const float*)d_in[3];
    const float* wp = (const float*)d_in[4];

    u16* ws = (u16*)d_ws;
    const size_t XS = (size_t)B_ * T_ * D_;
    const size_t WT = (size_t)D_ * D_;
    const size_t HS = (size_t)B_ * H_ * T_ * DK_;
    u16* xb = ws;                    // x as bf16
    u16* wt = xb + XS;               // 4 transposed weights
    u16* q  = wt + 4 * WT;           // Q, K, VT each HS
    u16* k  = q + HS;
    u16* vt = k + HS;
    u16* ao = vt + HS;               // attention out bf16 [B*T][D]
    float* pL = (float*)(ao + HS);               // 2 * BH * T floats
    float* pO = pL + 2 * (size_t)BH_ * T_;       // 2 * BH * T * DK floats

    prep_kernel<<<dim3(3072 + 2304), 256, 0, stream>>>(x, wq, wk, wv, wp, xb, wt);
    gemm_bt<0><<<dim3(1152), 256, 0, stream>>>(xb, wt, q);
    attn_kernel<<<dim3(768), 512, 0, stream>>>(q, k, vt, pO, pL);
    combine_kernel<<<dim3(64, 24), 256, 0, stream>>>(pO, pL, ao);
    gemm_bt<1><<<dim3(384), 256, 0, stream>>>(ao, wt + 3 * WT, d_out);
}

// Round 13
// 251.114 us; speedup vs baseline: 1.0162x; 1.0162x over previous
//
#include <hip/hip_runtime.h>
#include <stdint.h>

#define B_ 2
#define T_ 4096
#define D_ 768
#define H_ 12
#define DK_ 64
#define BH_ 24

typedef unsigned short u16;
typedef unsigned int u32;
typedef __bf16 bf16x8 __attribute__((ext_vector_type(8)));
typedef float f32x4 __attribute__((ext_vector_type(4)));
typedef short s16x8 __attribute__((ext_vector_type(8)));

__device__ __forceinline__ float exp2_raw(float x) {
#if __has_builtin(__builtin_amdgcn_exp2f)
    return __builtin_amdgcn_exp2f(x);
#else
    float y; asm("v_exp_f32 %0, %1" : "=v"(y) : "v"(x)); return y;
#endif
}

__device__ __forceinline__ f32x4 mfma16(bf16x8 a, bf16x8 b, f32x4 c) {
    return __builtin_amdgcn_mfma_f32_16x16x32_bf16(a, b, c, 0, 0, 0);
}

__device__ __forceinline__ u16 f2bf(float f) {
    union { float f; u32 u; } v; v.f = f;
    u32 r = v.u + 0x7FFFu + ((v.u >> 16) & 1u);
    return (u16)(r >> 16);
}

// pack two floats to bf16 pair (lo | hi<<16), round-half-up, via v_perm
__device__ __forceinline__ u32 pack2bf(float lo, float hi) {
    union { float f; u32 u; } a, b; a.f = lo; b.f = hi;
    return __builtin_amdgcn_perm(b.u + 0x8000u, a.u + 0x8000u, 0x07060302u);
}

// async 16B global->LDS; lds base must be wave-uniform, lane i lands at base+i*16
__device__ __forceinline__ void gll16(const u16* g, u16* l) {
    __builtin_amdgcn_global_load_lds(
        (const __attribute__((address_space(1))) u32*)g,
        (__attribute__((address_space(3))) u32*)l, 16, 0, 0);
}

// ------- prep: x fp32->bf16 (bid<3072) + weight transpose (bid>=3072) -------
// merged to save one kernel-launch gap (~10us).
__global__ __launch_bounds__(256) void prep_kernel(
    const float* __restrict__ x,
    const float* __restrict__ w0, const float* __restrict__ w1,
    const float* __restrict__ w2, const float* __restrict__ w3,
    u16* __restrict__ xb, u16* __restrict__ wt)
{
    __shared__ u16 tile[32][33];
    int bid = blockIdx.x;
    if (bid < 3072) {
        int i = (bid * 256 + threadIdx.x) * 8;
        float4 a = *(const float4*)&x[i];
        float4 b = *(const float4*)&x[i + 4];
        uint4 dd;
        dd.x = pack2bf(a.x, a.y); dd.y = pack2bf(a.z, a.w);
        dd.z = pack2bf(b.x, b.y); dd.w = pack2bf(b.z, b.w);
        *(uint4*)&xb[i] = dd;
    } else {
        int id = bid - 3072;            // 2304 = 4 * 24 * 24
        int z = id / 576;
        int rest = id % 576;
        int by = rest / 24, bx = rest % 24;
        const float* src = (z == 0) ? w0 : (z == 1) ? w1 : (z == 2) ? w2 : w3;
        u16* dst = wt + (size_t)z * D_ * D_;
        int tx = threadIdx.x & 31, ty = threadIdx.x >> 5;
        int x0 = bx * 32, y0 = by * 32;
        for (int i = ty; i < 32; i += 8) tile[i][tx] = f2bf(src[(size_t)(y0 + i) * D_ + x0 + tx]);
        __syncthreads();
        for (int i = ty; i < 32; i += 8) dst[(size_t)(x0 + i) * D_ + y0 + tx] = tile[tx][i];
    }
}

// ---------------- GEMM: C[M][N] = A[M][K] * Bt[N][K]^T, K=768 ---------------
// m97-style: global_load_lds 16B staging, unpadded LDS with XOR chunk swizzle
// LDS[row][c8] holds global chunk c8 ^ (row&7); swizzle realized on global side.
// T1 XCD swizzle (flat grid): xcd = wgid%8 owns a CONTIGUOUS m-range (8 m-tiles
// x all n-tiles) -> per-XCD L2 working set = A-slice 1.6MB + full B (3.4/1.2MB)
// ~resident (R12: neutral vs 2D grid, kept for locality structure).
// MODE 0: A bf16 x, N=2304 fused QKV (Q scaled, K, V transposed). MODE 1: fp32 out.
template<int MODE>
__global__ __launch_bounds__(256) void gemm_bt(
    const u16* __restrict__ A, const u16* __restrict__ Bt, void* __restrict__ outv)
{
    __shared__ u16 As[128 * 64];
    __shared__ u16 Bs[128 * 64];
    const int K = 768;
    const int NT = (MODE == 0) ? 18 : 6;   // n-tiles
    int tid = threadIdx.x;
    int lane = tid & 63, wave = tid >> 6;
    int r = lane & 15, quad = lane >> 4;
    int rx = r & 7;

    // XCD-aware decode: 64 m-tiles = 8 per XCD, contiguous.
    int wgid = blockIdx.x;
    int xcd = wgid & 7, slot = wgid >> 3;      // slot in [0, 8*NT)
    int mt = xcd * 8 + slot / NT;
    int nt = slot % NT;
    int m0 = mt * 128, n0 = nt * 128;
    int wrow = (wave >> 1) * 64, wcol = (wave & 1) * 64;

    // staging: lane l covers row = wave*32 + j*8 + (l>>3), global chunk (l&7)^((l>>3)&7)
    int srow = wave * 32 + (lane >> 3);
    int scol = ((lane & 7) ^ (lane >> 3)) * 8;
    const u16* Ag = A + (size_t)(m0 + srow) * K + scol;
    const u16* Bg = Bt + (size_t)(n0 + srow) * K + scol;

    f32x4 acc[4][4];
    #pragma unroll
    for (int i = 0; i < 4; i++)
        #pragma unroll
        for (int j = 0; j < 4; j++)
            #pragma unroll
            for (int e = 0; e < 4; e++) acc[i][j][e] = 0.f;

    for (int k0 = 0; k0 < K; k0 += 64) {
        __syncthreads();
        #pragma unroll
        for (int j = 0; j < 4; j++) {
            gll16(Ag + (size_t)j * 8 * K + k0, As + (wave * 32 + j * 8) * 64);
            gll16(Bg + (size_t)j * 8 * K + k0, Bs + (wave * 32 + j * 8) * 64);
        }
        __syncthreads();
        #pragma unroll
        for (int ks = 0; ks < 2; ks++) {
            int swz = ((ks * 4 + quad) ^ rx) * 8;
            bf16x8 af[4], bfr[4];
            #pragma unroll
            for (int mi = 0; mi < 4; mi++)
                af[mi] = *(const bf16x8*)&As[(wrow + mi * 16 + r) * 64 + swz];
            #pragma unroll
            for (int ni = 0; ni < 4; ni++)
                bfr[ni] = *(const bf16x8*)&Bs[(wcol + ni * 16 + r) * 64 + swz];
            #pragma unroll
            for (int mi = 0; mi < 4; mi++)
                #pragma unroll
                for (int ni = 0; ni < 4; ni++)
                    acc[mi][ni] = mfma16(af[mi], bfr[ni], acc[mi][ni]);
        }
    }

    if (MODE == 0) {
        u16* out = (u16*)outv;
        int which = n0 / D_;
        int nb = n0 % D_;
        const size_t HS = (size_t)B_ * H_ * T_ * DK_;
        if (which == 2) {
            u16* vt = out + 2 * HS;
            #pragma unroll
            for (int mi = 0; mi < 4; mi++) {
                int mg = m0 + wrow + mi * 16 + quad * 4;
                int b = mg >> 12, t = mg & 4095;
                #pragma unroll
                for (int ni = 0; ni < 4; ni++) {
                    int ng = nb + wcol + ni * 16 + r;
                    int h = ng >> 6, dk = ng & 63;
                    uint2 d;
                    d.x = pack2bf(acc[mi][ni][0], acc[mi][ni][1]);
                    d.y = pack2bf(acc[mi][ni][2], acc[mi][ni][3]);
                    *(uint2*)&vt[(((size_t)(b * H_ + h)) * DK_ + dk) * T_ + t] = d;
                }
            }
        } else {
            const float cf = (which == 0) ? 0.18033688011112042f : 1.0f; // 0.125*log2(e)
            size_t wbase = (size_t)which * HS;
            #pragma unroll
            for (int mi = 0; mi < 4; mi++) {
                #pragma unroll
                for (int ni = 0; ni < 4; ni++) {
                    int ng = nb + wcol + ni * 16 + r;
                    int h = ng >> 6, dk = ng & 63;
                    #pragma unroll
                    for (int e = 0; e < 4; e++) {
                        int mg = m0 + wrow + mi * 16 + quad * 4 + e;
                        int b = mg >> 12, t = mg & 4095;
                        out[wbase + (((size_t)(b * H_ + h)) * T_ + t) * DK_ + dk]
                            = f2bf(acc[mi][ni][e] * cf);
                    }
                }
            }
        }
    } else {
        float* out = (float*)outv;
        #pragma unroll
        for (int mi = 0; mi < 4; mi++)
            #pragma unroll
            for (int ni = 0; ni < 4; ni++)
                #pragma unroll
                for (int e = 0; e < 4; e++)
                    out[(size_t)(m0 + wrow + mi * 16 + quad * 4 + e) * D_ + n0 + wcol + ni * 16 + r]
                        = acc[mi][ni][e];
    }
}

// ---------------- flash attention: S^T, no-max, KV-split, q=32/wave ---------
// Q (pre-scaled), K: [bh][t][dk]; VT: [bh][dk][t]
// Block: 512 threads = 8 waves x 32 q rows (256 q per block), kv tile 128.
// P stays IN REGISTERS: QK^T MFMA (s,p) feeds K rows perm(i)=s*32+(i>>2)*8+p*4+(i&3),
// so each lane's C-rows (quad*4+e) land exactly on its PV B-fragment kv slots
// (kv = s*32+quad*8+j), s in 0..3. No Pt LDS buffer, no cross-lane exchange.
// V held as TWO [64][64] subtiles per buffer (R9: conflict-free).
// T3 minimum-2-phase with COMPILE-TIME ping-pong: STAGE(next buf) issued before
// COMPUTE(cur buf); the vmcnt(0) inside the single per-tile __syncthreads then
// drains loads issued a full compute phase earlier (hidden).
// T5 setprio: ONE coarse setprio(1)/(0) pair around the whole MFMA-dense
// compute_tile (2 blocks/CU give stage-vs-compute wave role diversity; R1's
// failure was per-MFMA toggling + sched_barriers, not the mechanism).
// Staging via global_load_lds: linear LDS dest + pre-XOR'd global chunk (rule #21).
// T1 XCD swizzle: flat 768-block grid; xcd = wgid%8 owns 3 bh -> K+V (3MB) in L2.
__global__ __launch_bounds__(512, 4) void attn_kernel(
    const u16* __restrict__ Q, const u16* __restrict__ K,
    const u16* __restrict__ VT, float* __restrict__ pO, float* __restrict__ pL)
{
    __shared__ u16 Ks[2][128 * 64];      // [buf][kv][dk], chunk-swizzled
    __shared__ u16 Vs[2][2][64 * 64];    // [buf][kvhalf][dk][kv64], chunk-swizzled

    int tid = threadIdx.x;
    int lane = tid & 63, w = tid >> 6;       // w in [0,8)
    int r = lane & 15, quad = lane >> 4;

    // XCD-aware decode of flat wgid (768 = 8 xcd * 3 bh * 2 z * 16 qblk)
    int wgid = blockIdx.x;
    int xcd = wgid & 7, slot = wgid >> 3;
    int bh = xcd * 3 + (slot >> 5);
    int rem = slot & 31;
    int z = rem >> 4;
    int q0 = (rem & 15) * 256;

    bf16x8 qf[2][2];
    #pragma unroll
    for (int qi = 0; qi < 2; qi++) {
        const u16* Qb = Q + ((size_t)bh * T_ + q0 + w * 32 + qi * 16 + r) * DK_;
        qf[qi][0] = *(const bf16x8*)(Qb + quad * 8);
        qf[qi][1] = *(const bf16x8*)(Qb + 32 + quad * 8);
    }

    bf16x8 ones;
    #pragma unroll
    for (int j = 0; j < 8; j++) ones[j] = (__bf16)1.0f;

    f32x4 fzero;
    #pragma unroll
    for (int e = 0; e < 4; e++) fzero[e] = 0.f;

    f32x4 o[2][4];      // [qi][ndk]
    f32x4 lacc[2];
    #pragma unroll
    for (int qi = 0; qi < 2; qi++) {
        #pragma unroll
        for (int e = 0; e < 4; e++) lacc[qi][e] = 0.f;
        #pragma unroll
        for (int n = 0; n < 4; n++)
            #pragma unroll
            for (int e = 0; e < 4; e++) o[qi][n][e] = 0.f;
    }

    int kb0 = z * (T_ / 2), kb1 = kb0 + T_ / 2;
    int rb = ((r >> 2) * 8) + (r & 3);   // base of permuted K row for this lane

    // K staging: wave w stages rows w*16+(lane>>3) and w*16+8+(lane>>3).
    // f(row): group1 row>>3 = 2w (even) -> f=(lane>>3)&3; group2 -> f^4.
    int kls = lane >> 3;
    int sgcK1 = (lane & 7) ^ (kls & 3);
    const u16* KgA = K + ((size_t)bh * T_ + w * 16 + kls) * DK_ + sgcK1 * 8;
    const u16* KgB = K + ((size_t)bh * T_ + w * 16 + 8 + kls) * DK_ + (sgcK1 ^ 4) * 8;

    // V staging (R7 pattern per subtile): wave w covers dk rows w*8+(lane>>3),
    // local chunk (lane&7)^f(row); subtile j covers kv kb+j*64.
    int srow = w * 8 + (lane >> 3);
    int sfr = (w & 1) * 4 + ((lane >> 3) & 3);      // f(srow)
    int sgcV = (lane & 7) ^ sfr;
    const u16* Vg = VT + ((size_t)bh * DK_ + srow) * T_ + sgcV * 8;

    // per-buffer LDS staging bases (compile-time buffer selection)
    u16* KsA0 = &Ks[0][(w * 16) * 64];
    u16* KsB0 = &Ks[0][(w * 16 + 8) * 64];
    u16* KsA1 = &Ks[1][(w * 16) * 64];
    u16* KsB1 = &Ks[1][(w * 16 + 8) * 64];
    u16* V00 = &Vs[0][0][(w * 8) * 64];
    u16* V01 = &Vs[0][1][(w * 8) * 64];
    u16* V10 = &Vs[1][0][(w * 8) * 64];
    u16* V11 = &Vs[1][1][(w * 8) * 64];

    auto stage_tile = [&](int kb, u16* ksA, u16* ksB, u16* vs0, u16* vs1) {
        gll16(KgA + (size_t)kb * DK_, ksA);
        gll16(KgB + (size_t)kb * DK_, ksB);
        gll16(Vg + kb, vs0);
        gll16(Vg + kb + 64, vs1);
    };

    auto compute_tile = [&](const u16* Kc, const u16* V0, const u16* V1) {
        __builtin_amdgcn_s_setprio(1);
        #pragma unroll
        for (int s = 0; s < 4; s++) {
            // K fragments, permuted rows: p=0 -> rowA, p=1 -> rowB
            int rowA = s * 32 + rb;
            int rowB = rowA + 4;
            int fA = ((rowA >> 3) & 1) * 4 + (rowA & 3);
            int fB = ((rowB >> 3) & 1) * 4 + (rowB & 3);
            bf16x8 kA0 = *(const bf16x8*)&Kc[rowA * 64 + (quad ^ fA) * 8];
            bf16x8 kA1 = *(const bf16x8*)&Kc[rowA * 64 + (((4 + quad) ^ fA)) * 8];
            bf16x8 kB0 = *(const bf16x8*)&Kc[rowB * 64 + (quad ^ fB) * 8];
            bf16x8 kB1 = *(const bf16x8*)&Kc[rowB * 64 + (((4 + quad) ^ fB)) * 8];
            // V fragments: subtile s>>1, local chunk ((s&1)*4+quad) ^ f(row)
            const u16* Vsub = (s < 2) ? V0 : V1;
            bf16x8 vf[4];
            #pragma unroll
            for (int ndk = 0; ndk < 4; ndk++) {
                int row = ndk * 16 + r;
                int fvr = ((row >> 3) & 1) * 4 + (row & 3);
                vf[ndk] = *(const bf16x8*)&Vsub[row * 64 + ((((s & 1) * 4 + quad) ^ fvr)) * 8];
            }
            #pragma unroll
            for (int qi = 0; qi < 2; qi++) {
                f32x4 zA, zB;
                zA = mfma16(kA0, qf[qi][0], fzero);
                zA = mfma16(kA1, qf[qi][1], zA);
                zB = mfma16(kB0, qf[qi][0], fzero);
                zB = mfma16(kB1, qf[qi][1], zB);
                // P fragment: lane's 8 slots = kv s*32+quad*8+{0..7}, q col = qi*16+r
                bf16x8 pf;
                pf[0] = (__bf16)exp2_raw(zA[0]);
                pf[1] = (__bf16)exp2_raw(zA[1]);
                pf[2] = (__bf16)exp2_raw(zA[2]);
                pf[3] = (__bf16)exp2_raw(zA[3]);
                pf[4] = (__bf16)exp2_raw(zB[0]);
                pf[5] = (__bf16)exp2_raw(zB[1]);
                pf[6] = (__bf16)exp2_raw(zB[2]);
                pf[7] = (__bf16)exp2_raw(zB[3]);
                lacc[qi] = mfma16(ones, pf, lacc[qi]);
                #pragma unroll
                for (int ndk = 0; ndk < 4; ndk++)
                    o[qi][ndk] = mfma16(vf[ndk], pf, o[qi][ndk]);
            }
        }
        __builtin_amdgcn_s_setprio(0);
    };

    // prologue: stage first tile into buf0
    stage_tile(kb0, KsA0, KsB0, V00, V01);
    __syncthreads();

    for (int kb = kb0; kb < kb1; kb += 256) {
        // issue next tile into buf1; latency hides under compute(buf0)
        stage_tile(kb + 128, KsA1, KsB1, V10, V11);
        compute_tile(Ks[0], Vs[0][0], Vs[0][1]);
        __syncthreads();   // buf1 staged loads drained (hidden); buf0 free
        if (kb + 256 < kb1)
            stage_tile(kb + 256, KsA0, KsB0, V00, V01);
        compute_tile(Ks[1], Vs[1][0], Vs[1][1]);
        __syncthreads();   // buf0 staged loads drained; buf1 free
    }

    // partial epilogue: pO[z][bh][q][dk] fp32, pL[z][bh][q]
    const size_t SP = (size_t)BH_ * T_ * DK_;
    #pragma unroll
    for (int qi = 0; qi < 2; qi++) {
        int q = q0 + w * 32 + qi * 16 + r;
        float* base = pO + (size_t)z * SP + ((size_t)bh * T_ + q) * DK_;
        #pragma unroll
        for (int ndk = 0; ndk < 4; ndk++)
            *(f32x4*)&base[ndk * 16 + quad * 4] = o[qi][ndk];
    }
    if (quad == 0) {
        #pragma unroll
        for (int qi = 0; qi < 2; qi++)
            pL[(size_t)z * BH_ * T_ + (size_t)bh * T_ + q0 + w * 32 + qi * 16 + r]
                = lacc[qi][0];
    }
}

// ---------------- combine: AO = (O0+O1)/(l0+l1), bf16 -----------------------
__global__ __launch_bounds__(256) void combine_kernel(
    const float* __restrict__ pO, const float* __restrict__ pL, u16* __restrict__ AO)
{
    const size_t SP = (size_t)BH_ * T_ * DK_;
    int bh = blockIdx.y;
    int b = bh / H_, h = bh % H_;
    int q = blockIdx.x * 64 + (threadIdx.x >> 2);
    int dk0 = (threadIdx.x & 3) * 16;
    size_t idx = ((size_t)bh * T_ + q) * DK_ + dk0;
    float l0 = pL[(size_t)bh * T_ + q];
    float l1 = pL[(size_t)BH_ * T_ + (size_t)bh * T_ + q];
    float inv = 1.0f / (l0 + l1);
    u16* dst = AO + ((size_t)b * T_ + q) * D_ + h * DK_ + dk0;
    #pragma unroll
    for (int i = 0; i < 2; i++) {
        float4 a0 = *(const float4*)&pO[idx + i * 8];
        float4 a1 = *(const float4*)&pO[idx + i * 8 + 4];
        float4 b0 = *(const float4*)&pO[SP + idx + i * 8];
        float4 b1 = *(const float4*)&pO[SP + idx + i * 8 + 4];
        uint4 dd;
        dd.x = pack2bf((a0.x + b0.x) * inv, (a0.y + b0.y) * inv);
        dd.y = pack2bf((a0.z + b0.z) * inv, (a0.w + b0.w) * inv);
        dd.z = pack2bf((a1.x + b1.x) * inv, (a1.y + b1.y) * inv);
        dd.w = pack2bf((a1.z + b1.z) * inv, (a1.w + b1.w) * inv);
        *(uint4*)&dst[i * 8] = dd;
    }
}

// ---------------- launch -----------------------------------------------------
extern "C" void kernel_launch(void* const* d_in, const int* in_sizes, int n_in,
                              void* d_out, int out_size, void* d_ws, size_t ws_size,
                              hipStream_t stream)
{
    const float* x  = (const float*)d_in[0];
    const float* wq = (const float*)d_in[1];
    const float* wk = (const float*)d_in[2];
    const float* wv = (const float*)d_in[3];
    const float* wp = (const float*)d_in[4];

    u16* ws = (u16*)d_ws;
    const size_t XS = (size_t)B_ * T_ * D_;
    const size_t WT = (size_t)D_ * D_;
    const size_t HS = (size_t)B_ * H_ * T_ * DK_;
    u16* xb = ws;                    // x as bf16
    u16* wt = xb + XS;               // 4 transposed weights
    u16* q  = wt + 4 * WT;           // Q, K, VT each HS
    u16* k  = q + HS;
    u16* vt = k + HS;
    u16* ao = vt + HS;               // attention out bf16 [B*T][D]
    float* pL = (float*)(ao + HS);               // 2 * BH * T floats
    float* pO = pL + 2 * (size_t)BH_ * T_;       // 2 * BH * T * DK floats

    prep_kernel<<<dim3(3072 + 2304), 256, 0, stream>>>(x, wq, wk, wv, wp, xb, wt);
    gemm_bt<0><<<dim3(1152), 256, 0, stream>>>(xb, wt, q);
    attn_kernel<<<dim3(768), 512, 0, stream>>>(q, k, vt, pO, pL);
    combine_kernel<<<dim3(64, 24), 256, 0, stream>>>(pO, pL, ao);
    gemm_bt<1><<<dim3(384), 256, 0, stream>>>(ao, wt + 3 * WT, d_out);
}